// Round 12
// baseline (317.894 us; speedup 1.0000x reference)
//
#include <hip/hip_runtime.h>
#include <hip/hip_bf16.h>
#include <stdint.h>

typedef __attribute__((ext_vector_type(8))) short bf16x8;
typedef __attribute__((ext_vector_type(4))) float f32x4;
typedef __attribute__((ext_vector_type(16))) float f32x16;
typedef __attribute__((ext_vector_type(4))) float floatv4;
typedef __attribute__((ext_vector_type(8))) unsigned short ushortx8;

// fp32 -> bf16 round-to-nearest-even (finite inputs)
__device__ __forceinline__ unsigned short f2bf(float f) {
  union { float f; uint32_t u; } c; c.f = f;
  uint32_t u = c.u;
  uint32_t r = (u + 0x7FFFu + ((u >> 16) & 1u)) >> 16;
  return (unsigned short)r;
}

__global__ void cvt_f32_to_bf16(const float* __restrict__ src,
                                unsigned short* __restrict__ dst,
                                size_t n8) {
  size_t i = (size_t)blockIdx.x * blockDim.x + threadIdx.x;
  size_t stride = (size_t)gridDim.x * blockDim.x;
  for (size_t j = i; j < n8; j += stride) {
    floatv4 v0 = ((const floatv4*)src)[j * 2];
    floatv4 v1 = ((const floatv4*)src)[j * 2 + 1];
    ushortx8 o;
    o[0] = f2bf(v0[0]); o[1] = f2bf(v0[1]); o[2] = f2bf(v0[2]); o[3] = f2bf(v0[3]);
    o[4] = f2bf(v1[0]); o[5] = f2bf(v1[1]); o[6] = f2bf(v1[2]); o[7] = f2bf(v1[3]);
    ((ushortx8*)dst)[j] = o;
  }
}

// ------------- 4-barrier 256x256 bf16 GEMM, 32x32x16 MFMA (C = A*B^T + bias) -------------
// 512 threads = 8 waves (2M x 4N), per-wave output 128x64 = 4 m-tiles x 2 n-tiles of 32x32.
// LDS 128 KiB: A[2buf][2half][128][64] + B[2buf][2half][128][64], bf16, read-side XOR
// swizzle (inverse pre-applied to global source of global_load_lds; mask (lane&7)*8 elems,
// identical involution to the 16x16 version since both A and B reads are 16B at
// row = tile+(lane&31), k = ks*16+(lane>>5)*8).
//
// r11 ledger with staging spread 2/0/4/2:
//  P0: read a0(8); stage B_s0(t+1); Q(a0,b0) [b0 pre-read at P3(t-1)]; BAR
//  P1: read b1(4); Q(a0,b1); BAR
//  P2: read a1(8); stage B_s1(t+2)+A_s0(t+2); Q(a1,b1); BAR
//  P3: stage A_s1(t+2); VMCNT(6); BAR; Q(a1,b0); read b0(t+1)
// vmcnt: entering P0 = 6 {B_s1,A_s0,A_s1}(t+1); +2(P0) = 8; +4(P2) = 12; +2(P3) = 14;
// VMCNT(6) completes the 8 oldest = tile t+1 exactly (incl. its P0-staged B_s0).
// Tails: t==Kt-2 -> VMCNT(0); t==Kt-1 -> no stage/read.
// WAR (stage >=1 closing-barrier after region's last ds_read retirement):
//  B_s0(t+1)@P0: region's prior reads (b0/b1 of t-1) retired by P1(t-1)-end at latest;
//  B_s1(t+2)@P2: b1(t) retired P1-end; b0(t) (wn>=2 waves) read P3(t-1), retired P0-end;
//  A_s0(t+2)@P2: a0(t) retired P0-end;  A_s1(t+2)@P3: a1(t) retired P2-end.
// b0-next read sits after the all-waves VMCNT+BAR (vmcnt is per-wave!).

#define BAR()    do { asm volatile("" ::: "memory"); __builtin_amdgcn_s_barrier(); asm volatile("" ::: "memory"); } while (0)
#define VMCNT(n) asm volatile("s_waitcnt vmcnt(" #n ")" ::: "memory")

// swizzled k-offset (elements) for k-step ks (0..3): khi = (lane>>5)*8, m7 = (lane&7)*8
#define KOFF(ks) (((unsigned)((ks) * 16 + khi)) ^ m7)

// stage one 128x64 half-tile (16 KiB) via 2x global_load_lds(16B)/thread.
#define STG(sp, lbase, h, t_) do {                                                 \
    const unsigned _lb = (lbase) + (unsigned)((((t_) & 1) * 2 + (h)) * 8192);      \
    const size_t _k0 = (size_t)((t_) << 6);                                        \
    _Pragma("unroll")                                                              \
    for (int _l = 0; _l < 2; ++_l) {                                               \
      __builtin_amdgcn_global_load_lds(                                            \
        (const __attribute__((address_space(1))) void*)((sp) + (size_t)(h) * hoff + (size_t)_l * l1off + _k0), \
        (__attribute__((address_space(3))) void*)&lds[_lb + (unsigned)((_l * 512 + widx * 64) * 8)], \
        16, 0, 0);                                                                 \
    }                                                                              \
  } while (0)

// read A m-half q (8 x ds_read_b128): m-tiles q*2+m2, rows +l31, k-steps 0..3
#define READ_A(dst, q, bo)                                                         \
  _Pragma("unroll")                                                                \
  for (int m2 = 0; m2 < 2; ++m2) {                                                 \
    const unsigned rb = Abase + (bo) + (unsigned)(((((q) * 2 + m2) * 32) + l31) * 64); \
    _Pragma("unroll")                                                              \
    for (int ks = 0; ks < 4; ++ks)                                                 \
      dst[m2 * 4 + ks] = *(const bf16x8*)&lds[rb + KOFF(ks)];                      \
  }

// read B n-tile nt (4 x ds_read_b128): rows brow + nt*32 + l31, k-steps 0..3
#define READ_B(dst, nt, bo)                                                        \
  {                                                                                \
    const unsigned rb = Bbase + (bo) + (brow + (unsigned)((nt) * 32) + (unsigned)l31) * 64u; \
    _Pragma("unroll")                                                              \
    for (int ks = 0; ks < 4; ++ks)                                                 \
      dst[ks] = *(const bf16x8*)&lds[rb + KOFF(ks)];                               \
  }

// one quadrant (q = m-half, h = n-tile) x K=64: 2 m2 x 4 ks = 8 MFMA (32x32x16)
#define QUAD(aF, bF, q, h)                                                         \
  _Pragma("unroll")                                                                \
  for (int ks = 0; ks < 4; ++ks) {                                                 \
    _Pragma("unroll")                                                              \
    for (int m2 = 0; m2 < 2; ++m2)                                                 \
      acc[(q)*2+m2][(h)] = __builtin_amdgcn_mfma_f32_32x32x16_bf16(                \
          aF[m2*4+ks], bF[ks], acc[(q)*2+m2][(h)], 0, 0, 0);                       \
  }

__global__ __launch_bounds__(512, 2)
void gemm8p_bt(const unsigned short* __restrict__ Ag,
               const unsigned short* __restrict__ Bg,
               const float* __restrict__ bias, float* __restrict__ C,
               int M, int N, int K)
{
  __shared__ __attribute__((aligned(128))) unsigned short lds[65536];   // 128 KiB
  const int tid  = threadIdx.x;
  const int lane = tid & 63;
  const int widx = tid >> 6;              // 8 waves
  const int wm   = widx >> 2;             // 0..1  (M-half of 256)
  const int wn   = widx & 3;              // 0..3  (N-quarter, 64 cols)

  int bid = blockIdx.x;
  const int nwg = gridDim.x;
  if ((nwg & 7) == 0) { const int cpx = nwg >> 3; bid = (bid & 7) * cpx + (bid >> 3); }
  const int nTN = N >> 8;
  const int tm = bid / nTN, tn = bid - tm * nTN;
  const int row0 = tm << 8, col0 = tn << 8;

  const int l31 = lane & 31;
  const int khi = (lane >> 5) * 8;                        // k-half within 16
  const unsigned m7 = (unsigned)((lane & 7) * 8);         // swizzle mask (elems)

  const int Kt = K >> 6;

  const unsigned Abase = (unsigned)(wm * 8192);               // + buf*16384
  const unsigned Bbase = 32768u + (unsigned)((wn >> 1) * 8192);
  const unsigned brow  = (unsigned)((wn & 1) * 64);

  // hoisted staging addressing: per-thread source bases (swizzle pre-applied)
  const int sr = tid >> 3;                                           // 0..63
  const unsigned sks = (unsigned)(((tid & 7) * 8) ^ ((sr & 7) * 8)); // swz k-off
  const size_t l1off = (size_t)64 * K;    // _l=1 -> +64 rows
  const size_t hoff  = (size_t)128 * K;   // half 1 -> +128 rows
  const unsigned short* sA = Ag + (size_t)(row0 + sr) * K + sks;
  const unsigned short* sB = Bg + (size_t)(col0 + sr) * K + sks;

  f32x16 acc[4][2] = {};                  // [m-tile][n-tile], 128 AGPR
  bf16x8 a0[8], a1[8], b0[4], b1[4];

  // ---- prologue: tile0 (4 halves) + {B_s1(1), A_s0(1), A_s1(1)} ----
  STG(sA, 0u,      0, 0);
  STG(sA, 0u,      1, 0);
  STG(sB, 32768u,  0, 0);
  STG(sB, 32768u,  1, 0);
  if (Kt > 1) {
    STG(sB, 32768u, 1, 1);
    STG(sA, 0u,     0, 1);
    STG(sA, 0u,     1, 1);
    VMCNT(6);                 // tile0's 8 loads complete; tile1's 6 in flight
  } else {
    VMCNT(0);
  }
  BAR();                      // ALL waves drained tile0 -> reads below safe
  READ_B(b0, 0, 0u);          // pre-read tile0's b0 (4 reads)

  for (int t = 0; t < Kt; ++t) {
    const unsigned bufo  = (unsigned)((t & 1) * 16384);
    const unsigned nbufo = (unsigned)(((t + 1) & 1) * 16384);

    // ---- P0: read a0(8); stage B_s0(t+1); Q(a0,b0); BAR
    READ_A(a0, 0, bufo);
    if (t < Kt - 1) STG(sB, 32768u, 0, t + 1);
    __builtin_amdgcn_s_setprio(1); QUAD(a0, b0, 0, 0); __builtin_amdgcn_s_setprio(0);
    BAR();

    // ---- P1: read b1(4); Q(a0,b1); BAR
    READ_B(b1, 1, bufo);
    __builtin_amdgcn_s_setprio(1); QUAD(a0, b1, 0, 1); __builtin_amdgcn_s_setprio(0);
    BAR();

    // ---- P2: read a1(8); stage B_s1(t+2)+A_s0(t+2); Q(a1,b1); BAR
    READ_A(a1, 1, bufo);
    if (t < Kt - 2) {
      STG(sB, 32768u, 1, t + 2);
      STG(sA, 0u,     0, t + 2);
    }
    __builtin_amdgcn_s_setprio(1); QUAD(a1, b1, 1, 1); __builtin_amdgcn_s_setprio(0);
    BAR();

    // ---- P3: stage A_s1(t+2); VMCNT (tile t+1 landed, every wave); BAR;
    //          Q(a1,b0); read next tile's b0 (grinds under Q, after old-b0 use)
    if (t < Kt - 2) {
      STG(sA, 0u, 1, t + 2);
      VMCNT(6);               // completes tile t+1's 4 halves; t+2's 6 in flight
    } else if (t == Kt - 2) {
      VMCNT(0);               // drain: tile Kt-1 fully landed
    }
    BAR();
    __builtin_amdgcn_s_setprio(1); QUAD(a1, b0, 1, 0); __builtin_amdgcn_s_setprio(0);
    if (t < Kt - 1) READ_B(b0, 0, nbufo);
  }

  // ---- epilogue: 32x32 C/D layout col=lane&31, row=(reg&3)+8*(reg>>2)+4*(lane>>5)
  #pragma unroll
  for (int nt = 0; nt < 2; ++nt) {
    const int col = col0 + wn * 64 + nt * 32 + l31;
    const float bv = bias[col];
    #pragma unroll
    for (int mt = 0; mt < 4; ++mt) {
      const int rb = row0 + wm * 128 + mt * 32 + (khi >> 1);   // +4*(lane>>5)
      #pragma unroll
      for (int reg = 0; reg < 16; ++reg) {
        const int row = rb + (reg & 3) + 8 * (reg >> 2);
        C[(size_t)row * N + col] = acc[mt][nt][reg] + bv;
      }
    }
  }
}

// ---------------- fallback: 128x128 2-phase kernel (round-1, verified) ----------------
template<bool BF16SRC>
__global__ __launch_bounds__(256)
void gemm_bt_kernel(const void* __restrict__ Ap, const void* __restrict__ Bp,
                    const float* __restrict__ bias, float* __restrict__ C,
                    int M, int N, int K)
{
  constexpr int BM = 128, BN = 128, BK = 64;
  __shared__ unsigned short As[BM * BK];
  __shared__ unsigned short Bs[BN * BK];

  const int nTN = N / BN;
  int bid = blockIdx.x;
  const int nwg = gridDim.x;
  if ((nwg & 7) == 0) { const int cpx = nwg >> 3; bid = (bid & 7) * cpx + (bid >> 3); }
  const int tm = bid / nTN, tn = bid % nTN;
  const int row0 = tm * BM, col0 = tn * BN;

  const int tid  = threadIdx.x;
  const int lane = tid & 63;
  const int wid  = tid >> 6;
  const int wm   = wid >> 1;
  const int wn   = wid & 1;

  f32x4 acc[4][4] = {};

  const unsigned short* A16 = (const unsigned short*)Ap;
  const unsigned short* B16 = (const unsigned short*)Bp;
  const float* A32 = (const float*)Ap;
  const float* B32 = (const float*)Bp;

  for (int k0 = 0; k0 < K; k0 += BK) {
    if constexpr (BF16SRC) {
      #pragma unroll
      for (int j = 0; j < 4; ++j) {
        const int c  = wid * 4 + j;
        const int r  = c * 8 + (lane >> 3);
        const int kk = (lane & 7) * 8;
        __builtin_amdgcn_global_load_lds(
            (const __attribute__((address_space(1))) void*)(A16 + (size_t)(row0 + r) * K + k0 + kk),
            (__attribute__((address_space(3))) void*)(&As[c * 512]), 16, 0, 0);
      }
      #pragma unroll
      for (int j = 0; j < 4; ++j) {
        const int c  = wid * 4 + j;
        const int r  = c * 8 + (lane >> 3);
        const int kk = (lane & 7) * 8;
        __builtin_amdgcn_global_load_lds(
            (const __attribute__((address_space(1))) void*)(B16 + (size_t)(col0 + r) * K + k0 + kk),
            (__attribute__((address_space(3))) void*)(&Bs[c * 512]), 16, 0, 0);
      }
    } else {
      #pragma unroll
      for (int j = 0; j < 4; ++j) {
        const int e = (j * 256 + tid) * 8;
        const int r = e >> 6, kk = e & 63;
        floatv4 v0 = *(const floatv4*)&A32[(size_t)(row0 + r) * K + k0 + kk];
        floatv4 v1 = *(const floatv4*)&A32[(size_t)(row0 + r) * K + k0 + kk + 4];
        ushortx8 o;
        o[0] = f2bf(v0[0]); o[1] = f2bf(v0[1]); o[2] = f2bf(v0[2]); o[3] = f2bf(v0[3]);
        o[4] = f2bf(v1[0]); o[5] = f2bf(v1[1]); o[6] = f2bf(v1[2]); o[7] = f2bf(v1[3]);
        *(ushortx8*)&As[e] = o;
      }
      #pragma unroll
      for (int j = 0; j < 4; ++j) {
        const int e = (j * 256 + tid) * 8;
        const int r = e >> 6, kk = e & 63;
        floatv4 v0 = *(const floatv4*)&B32[(size_t)(col0 + r) * K + k0 + kk];
        floatv4 v1 = *(const floatv4*)&B32[(size_t)(col0 + r) * K + k0 + kk + 4];
        ushortx8 o;
        o[0] = f2bf(v0[0]); o[1] = f2bf(v0[1]); o[2] = f2bf(v0[2]); o[3] = f2bf(v0[3]);
        o[4] = f2bf(v1[0]); o[5] = f2bf(v1[1]); o[6] = f2bf(v1[2]); o[7] = f2bf(v1[3]);
        *(ushortx8*)&Bs[e] = o;
      }
    }
    __syncthreads();

    #pragma unroll
    for (int kk = 0; kk < BK / 32; ++kk) {
      const int ko = kk * 32 + (lane >> 4) * 8;
      bf16x8 a[4], b[4];
      #pragma unroll
      for (int mi = 0; mi < 4; ++mi)
        a[mi] = *(const bf16x8*)&As[(wm * 64 + mi * 16 + (lane & 15)) * BK + ko];
      #pragma unroll
      for (int ni = 0; ni < 4; ++ni)
        b[ni] = *(const bf16x8*)&Bs[(wn * 64 + ni * 16 + (lane & 15)) * BK + ko];
      #pragma unroll
      for (int mi = 0; mi < 4; ++mi)
        #pragma unroll
        for (int ni = 0; ni < 4; ++ni)
          acc[mi][ni] = __builtin_amdgcn_mfma_f32_16x16x32_bf16(a[mi], b[ni], acc[mi][ni], 0, 0, 0);
    }
    __syncthreads();
  }

  #pragma unroll
  for (int mi = 0; mi < 4; ++mi) {
    #pragma unroll
    for (int ni = 0; ni < 4; ++ni) {
      const int col = col0 + wn * 64 + ni * 16 + (lane & 15);
      const float bv = bias[col];
      #pragma unroll
      for (int j = 0; j < 4; ++j) {
        const int row = row0 + wm * 64 + mi * 16 + (lane >> 4) * 4 + j;
        C[(size_t)row * N + col] = acc[mi][ni][j] + bv;
      }
    }
  }
}

extern "C" void kernel_launch(void* const* d_in, const int* in_sizes, int n_in,
                              void* d_out, int out_size, void* d_ws, size_t ws_size,
                              hipStream_t stream) {
  const float* x = (const float*)d_in[0];
  const float* w = (const float*)d_in[1];
  const float* b = (const float*)d_in[2];
  float* out = (float*)d_out;

  const int N = in_sizes[2];            // 4096
  const int K = in_sizes[1] / N;        // 4096
  const int M = in_sizes[0] / K;        // 8192

  const size_t needed = ((size_t)M * K + (size_t)N * K) * sizeof(unsigned short);

  if (ws_size >= needed) {
    unsigned short* Abf = (unsigned short*)d_ws;
    unsigned short* Bbf = Abf + (size_t)M * K;
    cvt_f32_to_bf16<<<2048, 256, 0, stream>>>(x, Abf, (size_t)M * K / 8);
    cvt_f32_to_bf16<<<2048, 256, 0, stream>>>(w, Bbf, (size_t)N * K / 8);
    if ((M % 256) == 0 && (N % 256) == 0 && (K % 64) == 0 && K >= 192) {
      const int grid = (M / 256) * (N / 256);
      gemm8p_bt<<<grid, 512, 0, stream>>>(Abf, Bbf, b, out, M, N, K);
    } else {
      const int grid = (M / 128) * (N / 128);
      gemm_bt_kernel<true><<<grid, 256, 0, stream>>>(Abf, Bbf, b, out, M, N, K);
    }
  } else {
    const int grid = (M / 128) * (N / 128);
    gemm_bt_kernel<false><<<grid, 256, 0, stream>>>(x, w, b, out, M, N, K);
  }
}

// Round 13
// 300.528 us; speedup vs baseline: 1.0578x; 1.0578x over previous
//
#include <hip/hip_runtime.h>
#include <hip/hip_bf16.h>
#include <stdint.h>

typedef __attribute__((ext_vector_type(8))) short bf16x8;
typedef __attribute__((ext_vector_type(4))) float f32x4;
typedef __attribute__((ext_vector_type(4))) float floatv4;
typedef __attribute__((ext_vector_type(8))) unsigned short ushortx8;

// fp32 -> bf16 round-to-nearest-even (finite inputs)
__device__ __forceinline__ unsigned short f2bf(float f) {
  union { float f; uint32_t u; } c; c.f = f;
  uint32_t u = c.u;
  uint32_t r = (u + 0x7FFFu + ((u >> 16) & 1u)) >> 16;
  return (unsigned short)r;
}

__global__ void cvt_f32_to_bf16(const float* __restrict__ src,
                                unsigned short* __restrict__ dst,
                                size_t n8) {
  size_t i = (size_t)blockIdx.x * blockDim.x + threadIdx.x;
  size_t stride = (size_t)gridDim.x * blockDim.x;
  for (size_t j = i; j < n8; j += stride) {
    floatv4 v0 = ((const floatv4*)src)[j * 2];
    floatv4 v1 = ((const floatv4*)src)[j * 2 + 1];
    ushortx8 o;
    o[0] = f2bf(v0[0]); o[1] = f2bf(v0[1]); o[2] = f2bf(v0[2]); o[3] = f2bf(v0[3]);
    o[4] = f2bf(v1[0]); o[5] = f2bf(v1[1]); o[6] = f2bf(v1[2]); o[7] = f2bf(v1[3]);
    ((ushortx8*)dst)[j] = o;
  }
}

// ------ 4-barrier 256x256 bf16 GEMM (C = A*B^T + bias), 2x-unrolled K loop ------
// 512 threads = 8 waves (2M x 4N), per-wave output 128x64, 16x16x32 MFMA.
// LDS 128 KiB: A[2buf][2half][128][64] + B[2buf][2half][128][64], bf16,
// read-side XOR swizzle k ^= (row&7)*8 (inverse pre-applied to global source).
//
// r11 ledger (proven r8/r11), with the K loop unrolled x2 so ALL LDS buffer
// offsets are compile-time literals: ds_read becomes base+imm (no per-iter
// VALU address chains), and the scheduler sees a 2-K-tile straight-line region.
//  P0: read a0(8); stage B_s0(t+1)->NBUF; Q(a0,b0) [b0 pre-read P3(t-1)]; BAR
//  P1: read b1(4); Q(a0,b1); BAR
//  P2: read a1(8); Q(a1,b1); BAR
//  P3: stage B_s1/A_s0/A_s1(t+2)->BUF; VMCNT(6); BAR; Q(a1,b0); read b0(t+1)<-NBUF
// vmcnt: entering P0 = 6 {B_s1,A_s0,A_s1}(t+1); +2(P0)=8; +6(P3)=14; VMCNT(6)
// completes the 8 oldest = tile t+1 exactly. Tails: VMCNT(0) at t==Kt-2.
// WAR: every staged region's ds_reads retired >=1 closing-barrier earlier.
// b0-next read sits after the all-waves VMCNT+BAR (vmcnt is per-wave!).
// Requires Kt even (launcher guards; else fallback kernel).

#define BAR()    do { asm volatile("" ::: "memory"); __builtin_amdgcn_s_barrier(); asm volatile("" ::: "memory"); } while (0)
#define VMCNT(n) asm volatile("s_waitcnt vmcnt(" #n ")" ::: "memory")

// stage one 128x64 half-tile (16 KiB) via 2x global_load_lds(16B)/thread.
// bufe = LITERAL buffer element-offset (0 / 16384); t_ only feeds the global k.
#define STG(sp, lbase, bufe, h, t_) do {                                           \
    const unsigned _lb = (lbase) + (bufe) + (unsigned)((h) * 8192);                \
    const size_t _k0 = (size_t)((t_) << 6);                                        \
    _Pragma("unroll")                                                              \
    for (int _l = 0; _l < 2; ++_l) {                                               \
      __builtin_amdgcn_global_load_lds(                                            \
        (const __attribute__((address_space(1))) void*)((sp) + (size_t)(h) * hoff + (size_t)_l * l1off + _k0), \
        (__attribute__((address_space(3))) void*)&lds[_lb + (unsigned)((_l * 512 + widx * 64) * 8)], \
        16, 0, 0);                                                                 \
    }                                                                              \
  } while (0)

// read A quad q (8 x ds_read_b128): rows q*64 + mi*16 + l15 of wave's A-half
#define READ_A(dst, q, bo)                                                         \
  _Pragma("unroll")                                                                \
  for (int mi = 0; mi < 4; ++mi) {                                                 \
    const unsigned rb = Abase + (bo) + (unsigned)((((q) * 64) + mi * 16 + l15) * 64); \
    dst[mi * 2 + 0] = *(const bf16x8*)&lds[rb + koff0];                            \
    dst[mi * 2 + 1] = *(const bf16x8*)&lds[rb + koff1];                            \
  }

// read B n-half h (4 x ds_read_b128): rows brow + h*32 + ni*16 + l15 of wave's B-half
#define READ_B(dst, h, bo)                                                         \
  _Pragma("unroll")                                                                \
  for (int ni = 0; ni < 2; ++ni) {                                                 \
    const unsigned rb = Bbase + (bo) + (brow + (unsigned)((h) * 32 + ni * 16 + l15)) * 64u; \
    dst[ni * 2 + 0] = *(const bf16x8*)&lds[rb + koff0];                            \
    dst[ni * 2 + 1] = *(const bf16x8*)&lds[rb + koff1];                            \
  }

// one C-quadrant (q = M-quad, h = N-half) x K=64: 4mi x 2ni x 2kk = 16 MFMA
#define QUAD(aF, bF, q, h)                                                         \
  _Pragma("unroll")                                                                \
  for (int mi = 0; mi < 4; ++mi) {                                                 \
    _Pragma("unroll")                                                              \
    for (int ni = 0; ni < 2; ++ni) {                                               \
      acc[(q)*4+mi][(h)*2+ni] = __builtin_amdgcn_mfma_f32_16x16x32_bf16(           \
          aF[mi*2+0], bF[ni*2+0], acc[(q)*4+mi][(h)*2+ni], 0, 0, 0);               \
      acc[(q)*4+mi][(h)*2+ni] = __builtin_amdgcn_mfma_f32_16x16x32_bf16(           \
          aF[mi*2+1], bF[ni*2+1], acc[(q)*4+mi][(h)*2+ni], 0, 0, 0);               \
    }                                                                              \
  }

// one K-tile: T = runtime tile index; BUFO/NBUFO = LITERAL element offsets
#define KTILE(T, BUFO, NBUFO) {                                                    \
    /* P0 */                                                                       \
    READ_A(a0, 0, BUFO);                                                           \
    if ((T) < Kt - 1) STG(sB, 32768u, NBUFO, 0, (T) + 1);                          \
    __builtin_amdgcn_s_setprio(1); QUAD(a0, b0, 0, 0); __builtin_amdgcn_s_setprio(0); \
    BAR();                                                                         \
    /* P1 */                                                                       \
    READ_B(b1, 1, BUFO);                                                           \
    __builtin_amdgcn_s_setprio(1); QUAD(a0, b1, 0, 1); __builtin_amdgcn_s_setprio(0); \
    BAR();                                                                         \
    /* P2 */                                                                       \
    READ_A(a1, 1, BUFO);                                                           \
    __builtin_amdgcn_s_setprio(1); QUAD(a1, b1, 1, 1); __builtin_amdgcn_s_setprio(0); \
    BAR();                                                                         \
    /* P3 */                                                                       \
    if ((T) < Kt - 2) {                                                            \
      STG(sB, 32768u, BUFO, 1, (T) + 2);                                           \
      STG(sA, 0u,     BUFO, 0, (T) + 2);                                           \
      STG(sA, 0u,     BUFO, 1, (T) + 2);                                           \
      VMCNT(6);                                                                    \
    } else if ((T) == Kt - 2) {                                                    \
      VMCNT(0);                                                                    \
    }                                                                              \
    BAR();                                                                         \
    __builtin_amdgcn_s_setprio(1); QUAD(a1, b0, 1, 0); __builtin_amdgcn_s_setprio(0); \
    if ((T) < Kt - 1) READ_B(b0, 0, NBUFO);                                        \
  }

__global__ __launch_bounds__(512, 2)
void gemm8p_bt(const unsigned short* __restrict__ Ag,
               const unsigned short* __restrict__ Bg,
               const float* __restrict__ bias, float* __restrict__ C,
               int M, int N, int K)
{
  __shared__ __attribute__((aligned(128))) unsigned short lds[65536];   // 128 KiB
  const int tid  = threadIdx.x;
  const int lane = tid & 63;
  const int widx = tid >> 6;              // 8 waves
  const int wm   = widx >> 2;             // 0..1  (M)
  const int wn   = widx & 3;              // 0..3  (N)

  int bid = blockIdx.x;
  const int nwg = gridDim.x;
  if ((nwg & 7) == 0) { const int cpx = nwg >> 3; bid = (bid & 7) * cpx + (bid >> 3); }
  const int nTN = N >> 8;
  const int tm = bid / nTN, tn = bid - tm * nTN;
  const int row0 = tm << 8, col0 = tn << 8;

  const int l15 = lane & 15, l16 = lane >> 4;
  const unsigned m7    = (unsigned)((lane & 7) * 8);      // per-lane XOR mask (elems)
  const unsigned koff0 = ((unsigned)(l16 * 8)) ^ m7;      // kk=0 swizzled k-offset
  const unsigned koff1 = ((unsigned)(32 + l16 * 8)) ^ m7; // kk=1

  const int Kt = K >> 6;

  const unsigned Abase = (unsigned)(wm * 8192);               // + buf literal
  const unsigned Bbase = 32768u + (unsigned)((wn >> 1) * 8192);
  const unsigned brow  = (unsigned)((wn & 1) * 64);

  // hoisted staging addressing: per-thread source bases (swizzle pre-applied)
  const int sr = tid >> 3;                                           // 0..63
  const unsigned sks = (unsigned)(((tid & 7) * 8) ^ ((sr & 7) * 8)); // swz k-off
  const size_t l1off = (size_t)64 * K;    // _l=1 -> +64 rows
  const size_t hoff  = (size_t)128 * K;   // half 1 -> +128 rows
  const unsigned short* sA = Ag + (size_t)(row0 + sr) * K + sks;
  const unsigned short* sB = Bg + (size_t)(col0 + sr) * K + sks;

  f32x4 acc[8][4] = {};
  bf16x8 a0[8], a1[8], b0[4], b1[4];

  // ---- prologue: tile0 (4 halves, buf0) + {B_s1, A_s0, A_s1}(tile1, buf1) ----
  STG(sA, 0u,     0u,     0, 0);
  STG(sA, 0u,     0u,     1, 0);
  STG(sB, 32768u, 0u,     0, 0);
  STG(sB, 32768u, 0u,     1, 0);
  if (Kt > 1) {
    STG(sB, 32768u, 16384u, 1, 1);
    STG(sA, 0u,     16384u, 0, 1);
    STG(sA, 0u,     16384u, 1, 1);
    VMCNT(6);                 // tile0's 8 loads complete; tile1's 6 in flight
  } else {
    VMCNT(0);
  }
  BAR();                      // ALL waves drained tile0 -> reads below safe
  READ_B(b0, 0, 0u);          // pre-read tile0's b0 (4 reads)

  // ---- main loop: 2 K-tiles per iteration, literal buffer offsets ----
  for (int t = 0; t < Kt; t += 2) {
    KTILE(t,     0u,     16384u);
    KTILE(t + 1, 16384u, 0u);
  }

  // ---- epilogue: C/D layout col=lane&15, row=(lane>>4)*4+j
  #pragma unroll
  for (int n = 0; n < 4; ++n) {
    const int col = col0 + wn * 64 + n * 16 + l15;
    const float bv = bias[col];
    #pragma unroll
    for (int mi8 = 0; mi8 < 8; ++mi8) {
      #pragma unroll
      for (int j = 0; j < 4; ++j) {
        const int row = row0 + wm * 128 + mi8 * 16 + l16 * 4 + j;
        C[(size_t)row * N + col] = acc[mi8][n][j] + bv;
      }
    }
  }
}

// ---------------- fallback: 128x128 2-phase kernel (round-1, verified) ----------------
template<bool BF16SRC>
__global__ __launch_bounds__(256)
void gemm_bt_kernel(const void* __restrict__ Ap, const void* __restrict__ Bp,
                    const float* __restrict__ bias, float* __restrict__ C,
                    int M, int N, int K)
{
  constexpr int BM = 128, BN = 128, BK = 64;
  __shared__ unsigned short As[BM * BK];
  __shared__ unsigned short Bs[BN * BK];

  const int nTN = N / BN;
  int bid = blockIdx.x;
  const int nwg = gridDim.x;
  if ((nwg & 7) == 0) { const int cpx = nwg >> 3; bid = (bid & 7) * cpx + (bid >> 3); }
  const int tm = bid / nTN, tn = bid % nTN;
  const int row0 = tm * BM, col0 = tn * BN;

  const int tid  = threadIdx.x;
  const int lane = tid & 63;
  const int wid  = tid >> 6;
  const int wm   = wid >> 1;
  const int wn   = wid & 1;

  f32x4 acc[4][4] = {};

  const unsigned short* A16 = (const unsigned short*)Ap;
  const unsigned short* B16 = (const unsigned short*)Bp;
  const float* A32 = (const float*)Ap;
  const float* B32 = (const float*)Bp;

  for (int k0 = 0; k0 < K; k0 += BK) {
    if constexpr (BF16SRC) {
      #pragma unroll
      for (int j = 0; j < 4; ++j) {
        const int c  = wid * 4 + j;
        const int r  = c * 8 + (lane >> 3);
        const int kk = (lane & 7) * 8;
        __builtin_amdgcn_global_load_lds(
            (const __attribute__((address_space(1))) void*)(A16 + (size_t)(row0 + r) * K + k0 + kk),
            (__attribute__((address_space(3))) void*)(&As[c * 512]), 16, 0, 0);
      }
      #pragma unroll
      for (int j = 0; j < 4; ++j) {
        const int c  = wid * 4 + j;
        const int r  = c * 8 + (lane >> 3);
        const int kk = (lane & 7) * 8;
        __builtin_amdgcn_global_load_lds(
            (const __attribute__((address_space(1))) void*)(B16 + (size_t)(col0 + r) * K + k0 + kk),
            (__attribute__((address_space(3))) void*)(&Bs[c * 512]), 16, 0, 0);
      }
    } else {
      #pragma unroll
      for (int j = 0; j < 4; ++j) {
        const int e = (j * 256 + tid) * 8;
        const int r = e >> 6, kk = e & 63;
        floatv4 v0 = *(const floatv4*)&A32[(size_t)(row0 + r) * K + k0 + kk];
        floatv4 v1 = *(const floatv4*)&A32[(size_t)(row0 + r) * K + k0 + kk + 4];
        ushortx8 o;
        o[0] = f2bf(v0[0]); o[1] = f2bf(v0[1]); o[2] = f2bf(v0[2]); o[3] = f2bf(v0[3]);
        o[4] = f2bf(v1[0]); o[5] = f2bf(v1[1]); o[6] = f2bf(v1[2]); o[7] = f2bf(v1[3]);
        *(ushortx8*)&As[e] = o;
      }
      #pragma unroll
      for (int j = 0; j < 4; ++j) {
        const int e = (j * 256 + tid) * 8;
        const int r = e >> 6, kk = e & 63;
        floatv4 v0 = *(const floatv4*)&B32[(size_t)(col0 + r) * K + k0 + kk];
        floatv4 v1 = *(const floatv4*)&B32[(size_t)(col0 + r) * K + k0 + kk + 4];
        ushortx8 o;
        o[0] = f2bf(v0[0]); o[1] = f2bf(v0[1]); o[2] = f2bf(v0[2]); o[3] = f2bf(v0[3]);
        o[4] = f2bf(v1[0]); o[5] = f2bf(v1[1]); o[6] = f2bf(v1[2]); o[7] = f2bf(v1[3]);
        *(ushortx8*)&Bs[e] = o;
      }
    }
    __syncthreads();

    #pragma unroll
    for (int kk = 0; kk < BK / 32; ++kk) {
      const int ko = kk * 32 + (lane >> 4) * 8;
      bf16x8 a[4], b[4];
      #pragma unroll
      for (int mi = 0; mi < 4; ++mi)
        a[mi] = *(const bf16x8*)&As[(wm * 64 + mi * 16 + (lane & 15)) * BK + ko];
      #pragma unroll
      for (int ni = 0; ni < 4; ++ni)
        b[ni] = *(const bf16x8*)&Bs[(wn * 64 + ni * 16 + (lane & 15)) * BK + ko];
      #pragma unroll
      for (int mi = 0; mi < 4; ++mi)
        #pragma unroll
        for (int ni = 0; ni < 4; ++ni)
          acc[mi][ni] = __builtin_amdgcn_mfma_f32_16x16x32_bf16(a[mi], b[ni], acc[mi][ni], 0, 0, 0);
    }
    __syncthreads();
  }

  #pragma unroll
  for (int mi = 0; mi < 4; ++mi) {
    #pragma unroll
    for (int ni = 0; ni < 4; ++ni) {
      const int col = col0 + wn * 64 + ni * 16 + (lane & 15);
      const float bv = bias[col];
      #pragma unroll
      for (int j = 0; j < 4; ++j) {
        const int row = row0 + wm * 64 + mi * 16 + (lane >> 4) * 4 + j;
        C[(size_t)row * N + col] = acc[mi][ni][j] + bv;
      }
    }
  }
}

extern "C" void kernel_launch(void* const* d_in, const int* in_sizes, int n_in,
                              void* d_out, int out_size, void* d_ws, size_t ws_size,
                              hipStream_t stream) {
  const float* x = (const float*)d_in[0];
  const float* w = (const float*)d_in[1];
  const float* b = (const float*)d_in[2];
  float* out = (float*)d_out;

  const int N = in_sizes[2];            // 4096
  const int K = in_sizes[1] / N;        // 4096
  const int M = in_sizes[0] / K;        // 8192

  const size_t needed = ((size_t)M * K + (size_t)N * K) * sizeof(unsigned short);

  if (ws_size >= needed) {
    unsigned short* Abf = (unsigned short*)d_ws;
    unsigned short* Bbf = Abf + (size_t)M * K;
    cvt_f32_to_bf16<<<2048, 256, 0, stream>>>(x, Abf, (size_t)M * K / 8);
    cvt_f32_to_bf16<<<2048, 256, 0, stream>>>(w, Bbf, (size_t)N * K / 8);
    const int Kt = K >> 6;
    if ((M % 256) == 0 && (N % 256) == 0 && (K % 64) == 0 && K >= 192 && (Kt % 2) == 0) {
      const int grid = (M / 256) * (N / 256);
      gemm8p_bt<<<grid, 512, 0, stream>>>(Abf, Bbf, b, out, M, N, K);
    } else {
      const int grid = (M / 128) * (N / 128);
      gemm_bt_kernel<true><<<grid, 256, 0, stream>>>(Abf, Bbf, b, out, M, N, K);
    }
  } else {
    const int grid = (M / 128) * (N / 128);
    gemm_bt_kernel<false><<<grid, 256, 0, stream>>>(x, w, b, out, M, N, K);
  }
}

// Round 15
// 298.996 us; speedup vs baseline: 1.0632x; 1.0051x over previous
//
#include <hip/hip_runtime.h>
#include <hip/hip_bf16.h>
#include <stdint.h>

typedef __attribute__((ext_vector_type(8))) short bf16x8;
typedef __attribute__((ext_vector_type(4))) float f32x4;
typedef __attribute__((ext_vector_type(4))) float floatv4;
typedef __attribute__((ext_vector_type(8))) unsigned short ushortx8;

// fp32 -> bf16 round-to-nearest-even (finite inputs)
__device__ __forceinline__ unsigned short f2bf(float f) {
  union { float f; uint32_t u; } c; c.f = f;
  uint32_t u = c.u;
  uint32_t r = (u + 0x7FFFu + ((u >> 16) & 1u)) >> 16;
  return (unsigned short)r;
}

__global__ void cvt_f32_to_bf16(const float* __restrict__ src,
                                unsigned short* __restrict__ dst,
                                size_t n8) {
  size_t i = (size_t)blockIdx.x * blockDim.x + threadIdx.x;
  size_t stride = (size_t)gridDim.x * blockDim.x;
  for (size_t j = i; j < n8; j += stride) {
    floatv4 v0 = ((const floatv4*)src)[j * 2];
    floatv4 v1 = ((const floatv4*)src)[j * 2 + 1];
    ushortx8 o;
    o[0] = f2bf(v0[0]); o[1] = f2bf(v0[1]); o[2] = f2bf(v0[2]); o[3] = f2bf(v0[3]);
    o[4] = f2bf(v1[0]); o[5] = f2bf(v1[1]); o[6] = f2bf(v1[2]); o[7] = f2bf(v1[3]);
    ((ushortx8*)dst)[j] = o;
  }
}

// ------ 4-barrier 256x256 bf16 GEMM (C = A*B^T + bias), 2x-unrolled K loop ------
// 512 threads = 8 waves (2M x 4N), per-wave output 128x64, 16x16x32 MFMA.
// LDS 128 KiB: A[2buf][2half][128][64] + B[2buf][2half][128][64], bf16,
// read-side XOR swizzle k ^= (row&7)*8 (inverse pre-applied to global source).
//
// r11 ledger (proven r8/r11/r13), K loop unrolled x2 so ALL LDS buffer offsets
// are compile-time literals (ds_read = base+imm, no per-iter VALU chains).
//  P0: read a0(8); stage B_s0(t+1)->NBUF; Q(a0,b0) [b0 pre-read P3(t-1)]; BAR
//  P1: read b1(4); Q(a0,b1); BAR
//  P2: read a1(8); Q(a1,b1); BAR
//  P3: stage B_s1/A_s0/A_s1(t+2)->BUF; VMCNT(6); BAR; Q(a1,b0); read b0(t+1)<-NBUF
// vmcnt: entering P0 = 6 {B_s1,A_s0,A_s1}(t+1); +2(P0)=8; +6(P3)=14; VMCNT(6)
// completes the 8 oldest = tile t+1 exactly. Tails: VMCNT(0) at t==Kt-2.
// WAR: every staged region's ds_reads retired >=1 closing-barrier earlier.
// b0-next read sits after the all-waves VMCNT+BAR (vmcnt is per-wave!).
// NOTE (r14 lesson): do NOT move stages earlier (e.g. A_s0(t+2)@P1) — the
// inline-asm barrier does not order register-only MFMAs, so the lgkm drain can
// sink past BAR and open a WAR window with same/next-phase staging (rule #18).
// Requires Kt even (launcher guards; else fallback kernel).

#define BAR()    do { asm volatile("" ::: "memory"); __builtin_amdgcn_s_barrier(); asm volatile("" ::: "memory"); } while (0)
#define VMCNT(n) asm volatile("s_waitcnt vmcnt(" #n ")" ::: "memory")

// stage one 128x64 half-tile (16 KiB) via 2x global_load_lds(16B)/thread.
// bufe = LITERAL buffer element-offset (0 / 16384); t_ only feeds the global k.
#define STG(sp, lbase, bufe, h, t_) do {                                           \
    const unsigned _lb = (lbase) + (bufe) + (unsigned)((h) * 8192);                \
    const size_t _k0 = (size_t)((t_) << 6);                                        \
    _Pragma("unroll")                                                              \
    for (int _l = 0; _l < 2; ++_l) {                                               \
      __builtin_amdgcn_global_load_lds(                                            \
        (const __attribute__((address_space(1))) void*)((sp) + (size_t)(h) * hoff + (size_t)_l * l1off + _k0), \
        (__attribute__((address_space(3))) void*)&lds[_lb + (unsigned)((_l * 512 + widx * 64) * 8)], \
        16, 0, 0);                                                                 \
    }                                                                              \
  } while (0)

// read A quad q (8 x ds_read_b128): rows q*64 + mi*16 + l15 of wave's A-half
#define READ_A(dst, q, bo)                                                         \
  _Pragma("unroll")                                                                \
  for (int mi = 0; mi < 4; ++mi) {                                                 \
    const unsigned rb = Abase + (bo) + (unsigned)((((q) * 64) + mi * 16 + l15) * 64); \
    dst[mi * 2 + 0] = *(const bf16x8*)&lds[rb + koff0];                            \
    dst[mi * 2 + 1] = *(const bf16x8*)&lds[rb + koff1];                            \
  }

// read B n-half h (4 x ds_read_b128): rows brow + h*32 + ni*16 + l15 of wave's B-half
#define READ_B(dst, h, bo)                                                         \
  _Pragma("unroll")                                                                \
  for (int ni = 0; ni < 2; ++ni) {                                                 \
    const unsigned rb = Bbase + (bo) + (brow + (unsigned)((h) * 32 + ni * 16 + l15)) * 64u; \
    dst[ni * 2 + 0] = *(const bf16x8*)&lds[rb + koff0];                            \
    dst[ni * 2 + 1] = *(const bf16x8*)&lds[rb + koff1];                            \
  }

// one C-quadrant (q = M-quad, h = N-half) x K=64: 4mi x 2ni x 2kk = 16 MFMA
#define QUAD(aF, bF, q, h)                                                         \
  _Pragma("unroll")                                                                \
  for (int mi = 0; mi < 4; ++mi) {                                                 \
    _Pragma("unroll")                                                              \
    for (int ni = 0; ni < 2; ++ni) {                                               \
      acc[(q)*4+mi][(h)*2+ni] = __builtin_amdgcn_mfma_f32_16x16x32_bf16(           \
          aF[mi*2+0], bF[ni*2+0], acc[(q)*4+mi][(h)*2+ni], 0, 0, 0);               \
      acc[(q)*4+mi][(h)*2+ni] = __builtin_amdgcn_mfma_f32_16x16x32_bf16(           \
          aF[mi*2+1], bF[ni*2+1], acc[(q)*4+mi][(h)*2+ni], 0, 0, 0);               \
    }                                                                              \
  }

// one K-tile: T = runtime tile index; BUFO/NBUFO = LITERAL element offsets
#define KTILE(T, BUFO, NBUFO) {                                                    \
    /* P0 */                                                                       \
    READ_A(a0, 0, BUFO);                                                           \
    if ((T) < Kt - 1) STG(sB, 32768u, NBUFO, 0, (T) + 1);                          \
    __builtin_amdgcn_s_setprio(1); QUAD(a0, b0, 0, 0); __builtin_amdgcn_s_setprio(0); \
    BAR();                                                                         \
    /* P1 */                                                                       \
    READ_B(b1, 1, BUFO);                                                           \
    __builtin_amdgcn_s_setprio(1); QUAD(a0, b1, 0, 1); __builtin_amdgcn_s_setprio(0); \
    BAR();                                                                         \
    /* P2 */                                                                       \
    READ_A(a1, 1, BUFO);                                                           \
    __builtin_amdgcn_s_setprio(1); QUAD(a1, b1, 1, 1); __builtin_amdgcn_s_setprio(0); \
    BAR();                                                                         \
    /* P3 */                                                                       \
    if ((T) < Kt - 2) {                                                            \
      STG(sB, 32768u, BUFO, 1, (T) + 2);                                           \
      STG(sA, 0u,     BUFO, 0, (T) + 2);                                           \
      STG(sA, 0u,     BUFO, 1, (T) + 2);                                           \
      VMCNT(6);                                                                    \
    } else if ((T) == Kt - 2) {                                                    \
      VMCNT(0);                                                                    \
    }                                                                              \
    BAR();                                                                         \
    __builtin_amdgcn_s_setprio(1); QUAD(a1, b0, 1, 0); __builtin_amdgcn_s_setprio(0); \
    if ((T) < Kt - 1) READ_B(b0, 0, NBUFO);                                        \
  }

__global__ __launch_bounds__(512, 2)
void gemm8p_bt(const unsigned short* __restrict__ Ag,
               const unsigned short* __restrict__ Bg,
               const float* __restrict__ bias, float* __restrict__ C,
               int M, int N, int K)
{
  __shared__ __attribute__((aligned(128))) unsigned short lds[65536];   // 128 KiB
  const int tid  = threadIdx.x;
  const int lane = tid & 63;
  const int widx = tid >> 6;              // 8 waves
  const int wm   = widx >> 2;             // 0..1  (M)
  const int wn   = widx & 3;              // 0..3  (N)

  int bid = blockIdx.x;
  const int nwg = gridDim.x;
  if ((nwg & 7) == 0) { const int cpx = nwg >> 3; bid = (bid & 7) * cpx + (bid >> 3); }
  const int nTN = N >> 8;
  const int tm = bid / nTN, tn = bid - tm * nTN;
  const int row0 = tm << 8, col0 = tn << 8;

  const int l15 = lane & 15, l16 = lane >> 4;
  const unsigned m7    = (unsigned)((lane & 7) * 8);      // per-lane XOR mask (elems)
  const unsigned koff0 = ((unsigned)(l16 * 8)) ^ m7;      // kk=0 swizzled k-offset
  const unsigned koff1 = ((unsigned)(32 + l16 * 8)) ^ m7; // kk=1

  const int Kt = K >> 6;

  const unsigned Abase = (unsigned)(wm * 8192);               // + buf literal
  const unsigned Bbase = 32768u + (unsigned)((wn >> 1) * 8192);
  const unsigned brow  = (unsigned)((wn & 1) * 64);

  // hoisted staging addressing: per-thread source bases (swizzle pre-applied)
  const int sr = tid >> 3;                                           // 0..63
  const unsigned sks = (unsigned)(((tid & 7) * 8) ^ ((sr & 7) * 8)); // swz k-off
  const size_t l1off = (size_t)64 * K;    // _l=1 -> +64 rows
  const size_t hoff  = (size_t)128 * K;   // half 1 -> +128 rows
  const unsigned short* sA = Ag + (size_t)(row0 + sr) * K + sks;
  const unsigned short* sB = Bg + (size_t)(col0 + sr) * K + sks;

  f32x4 acc[8][4] = {};
  bf16x8 a0[8], a1[8], b0[4], b1[4];

  // ---- prologue: tile0 (4 halves, buf0) + {B_s1, A_s0, A_s1}(tile1, buf1) ----
  STG(sA, 0u,     0u,     0, 0);
  STG(sA, 0u,     0u,     1, 0);
  STG(sB, 32768u, 0u,     0, 0);
  STG(sB, 32768u, 0u,     1, 0);
  if (Kt > 1) {
    STG(sB, 32768u, 16384u, 1, 1);
    STG(sA, 0u,     16384u, 0, 1);
    STG(sA, 0u,     16384u, 1, 1);
    VMCNT(6);                 // tile0's 8 loads complete; tile1's 6 in flight
  } else {
    VMCNT(0);
  }
  BAR();                      // ALL waves drained tile0 -> reads below safe
  READ_B(b0, 0, 0u);          // pre-read tile0's b0 (4 reads)

  // ---- main loop: 2 K-tiles per iteration, literal buffer offsets ----
  for (int t = 0; t < Kt; t += 2) {
    KTILE(t,     0u,     16384u);
    KTILE(t + 1, 16384u, 0u);
  }

  // ---- epilogue: C/D layout col=lane&15, row=(lane>>4)*4+j
  #pragma unroll
  for (int n = 0; n < 4; ++n) {
    const int col = col0 + wn * 64 + n * 16 + l15;
    const float bv = bias[col];
    #pragma unroll
    for (int mi8 = 0; mi8 < 8; ++mi8) {
      #pragma unroll
      for (int j = 0; j < 4; ++j) {
        const int row = row0 + wm * 128 + mi8 * 16 + l16 * 4 + j;
        C[(size_t)row * N + col] = acc[mi8][n][j] + bv;
      }
    }
  }
}

// ---------------- fallback: 128x128 2-phase kernel (round-1, verified) ----------------
template<bool BF16SRC>
__global__ __launch_bounds__(256)
void gemm_bt_kernel(const void* __restrict__ Ap, const void* __restrict__ Bp,
                    const float* __restrict__ bias, float* __restrict__ C,
                    int M, int N, int K)
{
  constexpr int BM = 128, BN = 128, BK = 64;
  __shared__ unsigned short As[BM * BK];
  __shared__ unsigned short Bs[BN * BK];

  const int nTN = N / BN;
  int bid = blockIdx.x;
  const int nwg = gridDim.x;
  if ((nwg & 7) == 0) { const int cpx = nwg >> 3; bid = (bid & 7) * cpx + (bid >> 3); }
  const int tm = bid / nTN, tn = bid % nTN;
  const int row0 = tm * BM, col0 = tn * BN;

  const int tid  = threadIdx.x;
  const int lane = tid & 63;
  const int wid  = tid >> 6;
  const int wm   = wid >> 1;
  const int wn   = wid & 1;

  f32x4 acc[4][4] = {};

  const unsigned short* A16 = (const unsigned short*)Ap;
  const unsigned short* B16 = (const unsigned short*)Bp;
  const float* A32 = (const float*)Ap;
  const float* B32 = (const float*)Bp;

  for (int k0 = 0; k0 < K; k0 += BK) {
    if constexpr (BF16SRC) {
      #pragma unroll
      for (int j = 0; j < 4; ++j) {
        const int c  = wid * 4 + j;
        const int r  = c * 8 + (lane >> 3);
        const int kk = (lane & 7) * 8;
        __builtin_amdgcn_global_load_lds(
            (const __attribute__((address_space(1))) void*)(A16 + (size_t)(row0 + r) * K + k0 + kk),
            (__attribute__((address_space(3))) void*)(&As[c * 512]), 16, 0, 0);
      }
      #pragma unroll
      for (int j = 0; j < 4; ++j) {
        const int c  = wid * 4 + j;
        const int r  = c * 8 + (lane >> 3);
        const int kk = (lane & 7) * 8;
        __builtin_amdgcn_global_load_lds(
            (const __attribute__((address_space(1))) void*)(B16 + (size_t)(col0 + r) * K + k0 + kk),
            (__attribute__((address_space(3))) void*)(&Bs[c * 512]), 16, 0, 0);
      }
    } else {
      #pragma unroll
      for (int j = 0; j < 4; ++j) {
        const int e = (j * 256 + tid) * 8;
        const int r = e >> 6, kk = e & 63;
        floatv4 v0 = *(const floatv4*)&A32[(size_t)(row0 + r) * K + k0 + kk];
        floatv4 v1 = *(const floatv4*)&A32[(size_t)(row0 + r) * K + k0 + kk + 4];
        ushortx8 o;
        o[0] = f2bf(v0[0]); o[1] = f2bf(v0[1]); o[2] = f2bf(v0[2]); o[3] = f2bf(v0[3]);
        o[4] = f2bf(v1[0]); o[5] = f2bf(v1[1]); o[6] = f2bf(v1[2]); o[7] = f2bf(v1[3]);
        *(ushortx8*)&As[e] = o;
      }
      #pragma unroll
      for (int j = 0; j < 4; ++j) {
        const int e = (j * 256 + tid) * 8;
        const int r = e >> 6, kk = e & 63;
        floatv4 v0 = *(const floatv4*)&B32[(size_t)(col0 + r) * K + k0 + kk];
        floatv4 v1 = *(const floatv4*)&B32[(size_t)(col0 + r) * K + k0 + kk + 4];
        ushortx8 o;
        o[0] = f2bf(v0[0]); o[1] = f2bf(v0[1]); o[2] = f2bf(v0[2]); o[3] = f2bf(v0[3]);
        o[4] = f2bf(v1[0]); o[5] = f2bf(v1[1]); o[6] = f2bf(v1[2]); o[7] = f2bf(v1[3]);
        *(ushortx8*)&Bs[e] = o;
      }
    }
    __syncthreads();

    #pragma unroll
    for (int kk = 0; kk < BK / 32; ++kk) {
      const int ko = kk * 32 + (lane >> 4) * 8;
      bf16x8 a[4], b[4];
      #pragma unroll
      for (int mi = 0; mi < 4; ++mi)
        a[mi] = *(const bf16x8*)&As[(wm * 64 + mi * 16 + (lane & 15)) * BK + ko];
      #pragma unroll
      for (int ni = 0; ni < 4; ++ni)
        b[ni] = *(const bf16x8*)&Bs[(wn * 64 + ni * 16 + (lane & 15)) * BK + ko];
      #pragma unroll
      for (int mi = 0; mi < 4; ++mi)
        #pragma unroll
        for (int ni = 0; ni < 4; ++ni)
          acc[mi][ni] = __builtin_amdgcn_mfma_f32_16x16x32_bf16(a[mi], b[ni], acc[mi][ni], 0, 0, 0);
    }
    __syncthreads();
  }

  #pragma unroll
  for (int mi = 0; mi < 4; ++mi) {
    #pragma unroll
    for (int ni = 0; ni < 4; ++ni) {
      const int col = col0 + wn * 64 + ni * 16 + (lane & 15);
      const float bv = bias[col];
      #pragma unroll
      for (int j = 0; j < 4; ++j) {
        const int row = row0 + wm * 64 + mi * 16 + (lane >> 4) * 4 + j;
        C[(size_t)row * N + col] = acc[mi][ni][j] + bv;
      }
    }
  }
}

extern "C" void kernel_launch(void* const* d_in, const int* in_sizes, int n_in,
                              void* d_out, int out_size, void* d_ws, size_t ws_size,
                              hipStream_t stream) {
  const float* x = (const float*)d_in[0];
  const float* w = (const float*)d_in[1];
  const float* b = (const float*)d_in[2];
  float* out = (float*)d_out;

  const int N = in_sizes[2];            // 4096
  const int K = in_sizes[1] / N;        // 4096
  const int M = in_sizes[0] / K;        // 8192

  const size_t needed = ((size_t)M * K + (size_t)N * K) * sizeof(unsigned short);

  if (ws_size >= needed) {
    unsigned short* Abf = (unsigned short*)d_ws;
    unsigned short* Bbf = Abf + (size_t)M * K;
    cvt_f32_to_bf16<<<2048, 256, 0, stream>>>(x, Abf, (size_t)M * K / 8);
    cvt_f32_to_bf16<<<2048, 256, 0, stream>>>(w, Bbf, (size_t)N * K / 8);
    const int Kt = K >> 6;
    if ((M % 256) == 0 && (N % 256) == 0 && (K % 64) == 0 && K >= 192 && (Kt % 2) == 0) {
      const int grid = (M / 256) * (N / 256);
      gemm8p_bt<<<grid, 512, 0, stream>>>(Abf, Bbf, b, out, M, N, K);
    } else {
      const int grid = (M / 128) * (N / 128);
      gemm_bt_kernel<true><<<grid, 256, 0, stream>>>(Abf, Bbf, b, out, M, N, K);
    }
  } else {
    const int grid = (M / 128) * (N / 128);
    gemm_bt_kernel<false><<<grid, 256, 0, stream>>>(x, w, b, out, M, N, K);
  }
}

// Round 16
// 287.172 us; speedup vs baseline: 1.1070x; 1.0412x over previous
//
#include <hip/hip_runtime.h>
#include <hip/hip_bf16.h>
#include <stdint.h>

typedef __attribute__((ext_vector_type(8))) short bf16x8;
typedef __attribute__((ext_vector_type(4))) float f32x4;
typedef __attribute__((ext_vector_type(4))) float floatv4;
typedef __attribute__((ext_vector_type(8))) unsigned short ushortx8;

// fp32 -> bf16 round-to-nearest-even (finite inputs)
__device__ __forceinline__ unsigned short f2bf(float f) {
  union { float f; uint32_t u; } c; c.f = f;
  uint32_t u = c.u;
  uint32_t r = (u + 0x7FFFu + ((u >> 16) & 1u)) >> 16;
  return (unsigned short)r;
}

// single kernel converts BOTH tensors (dst is contiguous: [x_bf16 | w_bf16])
__global__ void cvt_dual(const float* __restrict__ x, const float* __restrict__ w,
                         unsigned short* __restrict__ dst, size_t nx8, size_t nt8) {
  size_t i = (size_t)blockIdx.x * blockDim.x + threadIdx.x;
  size_t stride = (size_t)gridDim.x * blockDim.x;
  for (size_t j = i; j < nt8; j += stride) {
    const float* src = (j < nx8) ? x : w - nx8 * 8;   // src[j*8] indexes the right tensor
    floatv4 v0 = ((const floatv4*)src)[j * 2];
    floatv4 v1 = ((const floatv4*)src)[j * 2 + 1];
    ushortx8 o;
    o[0] = f2bf(v0[0]); o[1] = f2bf(v0[1]); o[2] = f2bf(v0[2]); o[3] = f2bf(v0[3]);
    o[4] = f2bf(v1[0]); o[5] = f2bf(v1[1]); o[6] = f2bf(v1[2]); o[7] = f2bf(v1[3]);
    ((ushortx8*)dst)[j] = o;
  }
}

// ------ 2-barrier-per-K-tile 256x256 bf16 GEMM (C = A*B^T + bias) ------
// 512 threads = 8 waves (2M x 4N), per-wave output 128x64, 16x16x32 MFMA.
// LDS 128 KiB: A[2buf][2half][128][64] + B[2buf][2half][128][64], bf16,
// read-side XOR swizzle k ^= (row&7)*8 (inverse pre-applied to global source).
//
// 2-phase schedule (A staged 1 tile ahead, B staged 2 tiles ahead):
//  P0(t): read a0(8)+b1(4) <-BUF; stage A_s0+A_s1(t+1)->NBUF;
//         Q(a0,b0)+Q(a0,b1); lgkmcnt(0); BAR
//  P1(t): read a1(8) <-BUF; stage B_s0+B_s1(t+2)->BUF;
//         Q(a1,b1)+Q(a1,b0); VMCNT(4); lgkmcnt(0); BAR; pre-read b0(t+1)<-NBUF
// vmcnt ledger (each STG = 2 loads; A-tile = B-tile = 4 loads):
//  entering P0(t): 4 outstanding {B(t+1)}; +4 (A(t+1)) = 8; +4 (B(t+2)) = 12;
//  VMCNT(4) completes the 8 oldest = B(t+1)+A(t+1) -> next tile fully staged
//  before BAR (all waves) -> pre-read b0(t+1) and P0(t+1) reads are safe.
//  Prologue: stage A(0),B(0),B(1) = 12 loads; VMCNT(4) completes A(0),B(0).
//  Tails: t==Kt-2 -> VMCNT(0); t==Kt-1 -> no stage/VMCNT/pre-read.
// WAR (stage >= 1 closing-barrier after the region's reads RETIRED):
//  the lgkmcnt(0) before EVERY closing BAR forces each wave's ds_reads to
//  retire before it passes the barrier (closes the r14 hazard: inline-asm
//  barriers don't order register-only MFMAs, so consumption alone is not a
//  retirement proof). Distances: A(t+1)@P0(t) after a0/a1(t-1) retired
//  P0/P1'(t-1) >=1 BAR; B(t+2)@P1'(t) after b1(t) retired P0(t)-end and
//  b0(t) (pre-read P1'(t-1), consumed P0(t)) retired P0(t)-end >=1 BAR.
// Requires Kt even (launcher guards; else fallback kernel).

#define BAR()     do { asm volatile("" ::: "memory"); __builtin_amdgcn_s_barrier(); asm volatile("" ::: "memory"); } while (0)
#define VMCNT(n)  asm volatile("s_waitcnt vmcnt(" #n ")" ::: "memory")
#define LGKM0()   asm volatile("s_waitcnt lgkmcnt(0)" ::: "memory")

// stage one 128x64 half-tile (16 KiB) via 2x global_load_lds(16B)/thread.
// bufe = LITERAL buffer element-offset (0 / 16384); t_ only feeds the global k.
#define STG(sp, lbase, bufe, h, t_) do {                                           \
    const unsigned _lb = (lbase) + (bufe) + (unsigned)((h) * 8192);                \
    const size_t _k0 = (size_t)((t_) << 6);                                        \
    _Pragma("unroll")                                                              \
    for (int _l = 0; _l < 2; ++_l) {                                               \
      __builtin_amdgcn_global_load_lds(                                            \
        (const __attribute__((address_space(1))) void*)((sp) + (size_t)(h) * hoff + (size_t)_l * l1off + _k0), \
        (__attribute__((address_space(3))) void*)&lds[_lb + (unsigned)((_l * 512 + widx * 64) * 8)], \
        16, 0, 0);                                                                 \
    }                                                                              \
  } while (0)

// read A quad q (8 x ds_read_b128): rows q*64 + mi*16 + l15 of wave's A-half
#define READ_A(dst, q, bo)                                                         \
  _Pragma("unroll")                                                                \
  for (int mi = 0; mi < 4; ++mi) {                                                 \
    const unsigned rb = Abase + (bo) + (unsigned)((((q) * 64) + mi * 16 + l15) * 64); \
    dst[mi * 2 + 0] = *(const bf16x8*)&lds[rb + koff0];                            \
    dst[mi * 2 + 1] = *(const bf16x8*)&lds[rb + koff1];                            \
  }

// read B n-half h (4 x ds_read_b128): rows brow + h*32 + ni*16 + l15 of wave's B-half
#define READ_B(dst, h, bo)                                                         \
  _Pragma("unroll")                                                                \
  for (int ni = 0; ni < 2; ++ni) {                                                 \
    const unsigned rb = Bbase + (bo) + (brow + (unsigned)((h) * 32 + ni * 16 + l15)) * 64u; \
    dst[ni * 2 + 0] = *(const bf16x8*)&lds[rb + koff0];                            \
    dst[ni * 2 + 1] = *(const bf16x8*)&lds[rb + koff1];                            \
  }

// one C-quadrant (q = M-quad, h = N-half) x K=64: 4mi x 2ni x 2kk = 16 MFMA
#define QUAD(aF, bF, q, h)                                                         \
  _Pragma("unroll")                                                                \
  for (int mi = 0; mi < 4; ++mi) {                                                 \
    _Pragma("unroll")                                                              \
    for (int ni = 0; ni < 2; ++ni) {                                               \
      acc[(q)*4+mi][(h)*2+ni] = __builtin_amdgcn_mfma_f32_16x16x32_bf16(           \
          aF[mi*2+0], bF[ni*2+0], acc[(q)*4+mi][(h)*2+ni], 0, 0, 0);               \
      acc[(q)*4+mi][(h)*2+ni] = __builtin_amdgcn_mfma_f32_16x16x32_bf16(           \
          aF[mi*2+1], bF[ni*2+1], acc[(q)*4+mi][(h)*2+ni], 0, 0, 0);               \
    }                                                                              \
  }

// one K-tile, 2 phases: T = runtime tile index; BUFO/NBUFO = LITERAL offsets
#define KTILE2(T, BUFO, NBUFO) {                                                   \
    /* P0: read a0,b1; stage A(t+1); Q(a0,b0)+Q(a0,b1); drain; BAR */              \
    READ_A(a0, 0, BUFO);                                                           \
    READ_B(b1, 1, BUFO);                                                           \
    if ((T) < Kt - 1) { STG(sA, 0u, NBUFO, 0, (T) + 1);                            \
                        STG(sA, 0u, NBUFO, 1, (T) + 1); }                          \
    __builtin_amdgcn_s_setprio(1);                                                 \
    QUAD(a0, b0, 0, 0); QUAD(a0, b1, 0, 1);                                        \
    __builtin_amdgcn_s_setprio(0);                                                 \
    LGKM0();                                                                       \
    BAR();                                                                         \
    /* P1: read a1; stage B(t+2); Q(a1,b1)+Q(a1,b0); VMCNT; drain; BAR; b0 */      \
    READ_A(a1, 1, BUFO);                                                           \
    if ((T) < Kt - 2) { STG(sB, 32768u, BUFO, 0, (T) + 2);                         \
                        STG(sB, 32768u, BUFO, 1, (T) + 2); }                       \
    __builtin_amdgcn_s_setprio(1);                                                 \
    QUAD(a1, b1, 1, 1); QUAD(a1, b0, 1, 0);                                        \
    __builtin_amdgcn_s_setprio(0);                                                 \
    if ((T) < Kt - 2)       { VMCNT(4); }                                          \
    else if ((T) == Kt - 2) { VMCNT(0); }                                          \
    LGKM0();                                                                       \
    BAR();                                                                         \
    if ((T) < Kt - 1) READ_B(b0, 0, NBUFO);                                        \
  }

__global__ __launch_bounds__(512, 2)
void gemm2p_bt(const unsigned short* __restrict__ Ag,
               const unsigned short* __restrict__ Bg,
               const float* __restrict__ bias, float* __restrict__ C,
               int M, int N, int K)
{
  __shared__ __attribute__((aligned(128))) unsigned short lds[65536];   // 128 KiB
  const int tid  = threadIdx.x;
  const int lane = tid & 63;
  const int widx = tid >> 6;              // 8 waves
  const int wm   = widx >> 2;             // 0..1  (M)
  const int wn   = widx & 3;              // 0..3  (N)

  int bid = blockIdx.x;
  const int nwg = gridDim.x;
  if ((nwg & 7) == 0) { const int cpx = nwg >> 3; bid = (bid & 7) * cpx + (bid >> 3); }
  const int nTN = N >> 8;
  const int tm = bid / nTN, tn = bid - tm * nTN;
  const int row0 = tm << 8, col0 = tn << 8;

  const int l15 = lane & 15, l16 = lane >> 4;
  const unsigned m7    = (unsigned)((lane & 7) * 8);      // per-lane XOR mask (elems)
  const unsigned koff0 = ((unsigned)(l16 * 8)) ^ m7;      // kk=0 swizzled k-offset
  const unsigned koff1 = ((unsigned)(32 + l16 * 8)) ^ m7; // kk=1

  const int Kt = K >> 6;

  const unsigned Abase = (unsigned)(wm * 8192);               // + buf literal
  const unsigned Bbase = 32768u + (unsigned)((wn >> 1) * 8192);
  const unsigned brow  = (unsigned)((wn & 1) * 64);

  // hoisted staging addressing: per-thread source bases (swizzle pre-applied)
  const int sr = tid >> 3;                                           // 0..63
  const unsigned sks = (unsigned)(((tid & 7) * 8) ^ ((sr & 7) * 8)); // swz k-off
  const size_t l1off = (size_t)64 * K;    // _l=1 -> +64 rows
  const size_t hoff  = (size_t)128 * K;   // half 1 -> +128 rows
  const unsigned short* sA = Ag + (size_t)(row0 + sr) * K + sks;
  const unsigned short* sB = Bg + (size_t)(col0 + sr) * K + sks;

  f32x4 acc[8][4] = {};
  bf16x8 a0[8], a1[8], b0[4], b1[4];

  // ---- prologue: A(0),B(0) -> buf0; B(1) -> buf1; complete tile0; pre-read b0(0)
  STG(sA, 0u,     0u,     0, 0);
  STG(sA, 0u,     0u,     1, 0);
  STG(sB, 32768u, 0u,     0, 0);
  STG(sB, 32768u, 0u,     1, 0);
  if (Kt > 1) {
    STG(sB, 32768u, 16384u, 0, 1);
    STG(sB, 32768u, 16384u, 1, 1);
    VMCNT(4);                 // completes A(0),B(0) (8 oldest); B(1)'s 4 in flight
  } else {
    VMCNT(0);
  }
  BAR();                      // ALL waves drained tile0 -> reads below safe
  READ_B(b0, 0, 0u);          // pre-read tile0's b0 (4 reads)

  // ---- main loop: 2 K-tiles per iteration, literal buffer offsets ----
  for (int t = 0; t < Kt; t += 2) {
    KTILE2(t,     0u,     16384u);
    KTILE2(t + 1, 16384u, 0u);
  }

  // ---- epilogue: C/D layout col=lane&15, row=(lane>>4)*4+j
  #pragma unroll
  for (int n = 0; n < 4; ++n) {
    const int col = col0 + wn * 64 + n * 16 + l15;
    const float bv = bias[col];
    #pragma unroll
    for (int mi8 = 0; mi8 < 8; ++mi8) {
      #pragma unroll
      for (int j = 0; j < 4; ++j) {
        const int row = row0 + wm * 128 + mi8 * 16 + l16 * 4 + j;
        C[(size_t)row * N + col] = acc[mi8][n][j] + bv;
      }
    }
  }
}

// ---------------- fallback: 128x128 2-phase kernel (round-1, verified) ----------------
template<bool BF16SRC>
__global__ __launch_bounds__(256)
void gemm_bt_kernel(const void* __restrict__ Ap, const void* __restrict__ Bp,
                    const float* __restrict__ bias, float* __restrict__ C,
                    int M, int N, int K)
{
  constexpr int BM = 128, BN = 128, BK = 64;
  __shared__ unsigned short As[BM * BK];
  __shared__ unsigned short Bs[BN * BK];

  const int nTN = N / BN;
  int bid = blockIdx.x;
  const int nwg = gridDim.x;
  if ((nwg & 7) == 0) { const int cpx = nwg >> 3; bid = (bid & 7) * cpx + (bid >> 3); }
  const int tm = bid / nTN, tn = bid % nTN;
  const int row0 = tm * BM, col0 = tn * BN;

  const int tid  = threadIdx.x;
  const int lane = tid & 63;
  const int wid  = tid >> 6;
  const int wm   = wid >> 1;
  const int wn   = wid & 1;

  f32x4 acc[4][4] = {};

  const unsigned short* A16 = (const unsigned short*)Ap;
  const unsigned short* B16 = (const unsigned short*)Bp;
  const float* A32 = (const float*)Ap;
  const float* B32 = (const float*)Bp;

  for (int k0 = 0; k0 < K; k0 += BK) {
    if constexpr (BF16SRC) {
      #pragma unroll
      for (int j = 0; j < 4; ++j) {
        const int c  = wid * 4 + j;
        const int r  = c * 8 + (lane >> 3);
        const int kk = (lane & 7) * 8;
        __builtin_amdgcn_global_load_lds(
            (const __attribute__((address_space(1))) void*)(A16 + (size_t)(row0 + r) * K + k0 + kk),
            (__attribute__((address_space(3))) void*)(&As[c * 512]), 16, 0, 0);
      }
      #pragma unroll
      for (int j = 0; j < 4; ++j) {
        const int c  = wid * 4 + j;
        const int r  = c * 8 + (lane >> 3);
        const int kk = (lane & 7) * 8;
        __builtin_amdgcn_global_load_lds(
            (const __attribute__((address_space(1))) void*)(B16 + (size_t)(col0 + r) * K + k0 + kk),
            (__attribute__((address_space(3))) void*)(&Bs[c * 512]), 16, 0, 0);
      }
    } else {
      #pragma unroll
      for (int j = 0; j < 4; ++j) {
        const int e = (j * 256 + tid) * 8;
        const int r = e >> 6, kk = e & 63;
        floatv4 v0 = *(const floatv4*)&A32[(size_t)(row0 + r) * K + k0 + kk];
        floatv4 v1 = *(const floatv4*)&A32[(size_t)(row0 + r) * K + k0 + kk + 4];
        ushortx8 o;
        o[0] = f2bf(v0[0]); o[1] = f2bf(v0[1]); o[2] = f2bf(v0[2]); o[3] = f2bf(v0[3]);
        o[4] = f2bf(v1[0]); o[5] = f2bf(v1[1]); o[6] = f2bf(v1[2]); o[7] = f2bf(v1[3]);
        *(ushortx8*)&As[e] = o;
      }
      #pragma unroll
      for (int j = 0; j < 4; ++j) {
        const int e = (j * 256 + tid) * 8;
        const int r = e >> 6, kk = e & 63;
        floatv4 v0 = *(const floatv4*)&B32[(size_t)(col0 + r) * K + k0 + kk];
        floatv4 v1 = *(const floatv4*)&B32[(size_t)(col0 + r) * K + k0 + kk + 4];
        ushortx8 o;
        o[0] = f2bf(v0[0]); o[1] = f2bf(v0[1]); o[2] = f2bf(v0[2]); o[3] = f2bf(v0[3]);
        o[4] = f2bf(v1[0]); o[5] = f2bf(v1[1]); o[6] = f2bf(v1[2]); o[7] = f2bf(v1[3]);
        *(ushortx8*)&Bs[e] = o;
      }
    }
    __syncthreads();

    #pragma unroll
    for (int kk = 0; kk < BK / 32; ++kk) {
      const int ko = kk * 32 + (lane >> 4) * 8;
      bf16x8 a[4], b[4];
      #pragma unroll
      for (int mi = 0; mi < 4; ++mi)
        a[mi] = *(const bf16x8*)&As[(wm * 64 + mi * 16 + (lane & 15)) * BK + ko];
      #pragma unroll
      for (int ni = 0; ni < 4; ++ni)
        b[ni] = *(const bf16x8*)&Bs[(wn * 64 + ni * 16 + (lane & 15)) * BK + ko];
      #pragma unroll
      for (int mi = 0; mi < 4; ++mi)
        #pragma unroll
        for (int ni = 0; ni < 4; ++ni)
          acc[mi][ni] = __builtin_amdgcn_mfma_f32_16x16x32_bf16(a[mi], b[ni], acc[mi][ni], 0, 0, 0);
    }
    __syncthreads();
  }

  #pragma unroll
  for (int mi = 0; mi < 4; ++mi) {
    #pragma unroll
    for (int ni = 0; ni < 4; ++ni) {
      const int col = col0 + wn * 64 + ni * 16 + (lane & 15);
      const float bv = bias[col];
      #pragma unroll
      for (int j = 0; j < 4; ++j) {
        const int row = row0 + wm * 64 + mi * 16 + (lane >> 4) * 4 + j;
        C[(size_t)row * N + col] = acc[mi][ni][j] + bv;
      }
    }
  }
}

extern "C" void kernel_launch(void* const* d_in, const int* in_sizes, int n_in,
                              void* d_out, int out_size, void* d_ws, size_t ws_size,
                              hipStream_t stream) {
  const float* x = (const float*)d_in[0];
  const float* w = (const float*)d_in[1];
  const float* b = (const float*)d_in[2];
  float* out = (float*)d_out;

  const int N = in_sizes[2];            // 4096
  const int K = in_sizes[1] / N;        // 4096
  const int M = in_sizes[0] / K;        // 8192

  const size_t needed = ((size_t)M * K + (size_t)N * K) * sizeof(unsigned short);

  if (ws_size >= needed) {
    unsigned short* Abf = (unsigned short*)d_ws;
    unsigned short* Bbf = Abf + (size_t)M * K;
    const size_t nx8 = (size_t)M * K / 8;
    const size_t nt8 = nx8 + (size_t)N * K / 8;
    cvt_dual<<<2048, 256, 0, stream>>>(x, w, Abf, nx8, nt8);
    const int Kt = K >> 6;
    if ((M % 256) == 0 && (N % 256) == 0 && (K % 64) == 0 && K >= 192 && (Kt % 2) == 0) {
      const int grid = (M / 256) * (N / 256);
      gemm2p_bt<<<grid, 512, 0, stream>>>(Abf, Bbf, b, out, M, N, K);
    } else {
      const int grid = (M / 128) * (N / 128);
      gemm_bt_kernel<true><<<grid, 256, 0, stream>>>(Abf, Bbf, b, out, M, N, K);
    }
  } else {
    const int grid = (M / 128) * (N / 128);
    gemm_bt_kernel<false><<<grid, 256, 0, stream>>>(x, w, b, out, M, N, K);
  }
}